// Round 1
// 249.622 us; speedup vs baseline: 1.0122x; 1.0122x over previous
//
#include <hip/hip_runtime.h>
#include <hip/hip_bf16.h>
#include <math.h>

#define N_NODES 50000
#define N_EDGES 800000
#define HEADS 4
#define HID 32
#define D1 128
#define D2 64
#define NEG_SLOPE 0.2f
#define LN_EPS 1e-5f

#define NB_SCAN ((N_NODES + 255) / 256)  // 196
#define CAP 64
#define GB1N 782                          // ceil(50000/64) gemm1 row-blocks
#define GB2N 782                          // gemm2 row-blocks
#define DEGB 784                          // degree blocks (grid-stride, ~4 edges/thread)
#define ILV (2 * GB1N)                    // 1564: interleave range for gemm/degree

typedef __attribute__((ext_vector_type(8))) short bf16x8;
typedef __attribute__((ext_vector_type(4))) float f32x4;

__device__ __forceinline__ float lrelu(float x) { return x > 0.f ? x : NEG_SLOPE * x; }
__device__ __forceinline__ float bf2f(__hip_bfloat16 v) { return __bfloat162float(v); }

__device__ __forceinline__ short f2bf_s(float x) {
    union { __hip_bfloat16 h; short s; } u;
    u.h = __float2bfloat16(x);
    return u.s;
}
__device__ __forceinline__ float bfs2f(short s) {
    union { unsigned u; float f; } v;
    v.u = ((unsigned)(unsigned short)s) << 16;
    return v.f;
}
__device__ __forceinline__ void split_bf(float x, short& hi, short& lo) {
    hi = f2bf_s(x);
    lo = f2bf_s(x - bfs2f(hi));
}

// ---------------- W prep: fragment-ordered bf16 hi/lo splits ----------------
// frag layout: frag_id = nt*4 + kt ; elem offset = fid*512 + l*8 + s
// value = W[kt*32 + (l>>4)*8 + s][nt*16 + (l&15)]
__global__ __launch_bounds__(256) void wprep_kernel(const float* __restrict__ W1,
                                                    const float* __restrict__ W2,
                                                    short* __restrict__ W1h, short* __restrict__ W1l,
                                                    short* __restrict__ W2h, short* __restrict__ W2l) {
    int idx = blockIdx.x * 256 + threadIdx.x;
    if (idx < 16384) {  // W1: 8 nt * 4 kt * 512
        int s = idx & 7, l = (idx >> 3) & 63, fid = idx >> 9;
        int kt = fid & 3, nt = fid >> 2;
        int k = kt * 32 + (l >> 4) * 8 + s;
        int n = nt * 16 + (l & 15);
        short hi, lo;
        split_bf(W1[k * 128 + n], hi, lo);
        W1h[idx] = hi;
        W1l[idx] = lo;
    } else if (idx < 16384 + 8192) {  // W2: 4 nt * 4 kt * 512
        int j = idx - 16384;
        int s = j & 7, l = (j >> 3) & 63, fid = j >> 9;
        int kt = fid & 3, nt = fid >> 2;
        int k = kt * 32 + (l >> 4) * 8 + s;
        int n = nt * 16 + (l & 15);
        short hi, lo;
        split_bf(W2[k * 64 + n], hi, lo);
        W2h[j] = hi;
        W2l[j] = lo;
    }
}

// ---------------- K1: MFMA gemm1 (+att1 epilogue) interleaved with degree/rank ----------------
// gemm block: 64 rows, 4 waves; wave w = head w owns cols [32w, 32w+32).
// 3-term bf16 split MFMA: xh*wh + xl*wh + xh*wl  (err ~2^-18, fp32-equivalent)
__global__ __launch_bounds__(256, 3) void gemm1_mfma_degree_kernel(
    const float* __restrict__ X, const short* __restrict__ Wh, const short* __restrict__ Wl,
    __hip_bfloat16* __restrict__ Y,
    const float* __restrict__ att_src, const float* __restrict__ att_dst,
    float* __restrict__ a_s, float* __restrict__ a_d,
    const int* __restrict__ dst, int* __restrict__ deg, int* __restrict__ rank) {
    int bid = blockIdx.x;
    bool isdeg;
    int id;
    if (bid < ILV) {  // interleave gemm/degree 1:1 so atomics spread over the dispatch
        isdeg = (bid & 1);
        id = bid >> 1;
    } else {
        isdeg = true;
        id = bid - ILV + GB1N;
    }
    if (isdeg) {
        int t0 = id * 256 + threadIdx.x;
        const int stride = DEGB * 256;
#pragma unroll
        for (int u = 0; u < 4; ++u) {
            int i = t0 + u * stride;
            if (i < N_EDGES) rank[i] = atomicAdd(&deg[dst[i]], 1);
        }
        return;
    }

    int tid = threadIdx.x;
    int w = tid >> 6;   // wave == head
    int l = tid & 63;
    int lr = l & 15;    // A: row-in-tile ; B/D: col-in-tile
    int lq = l >> 4;    // k-chunk / D row-group

    // persistent B fragments (8 hi + 8 lo = 64 VGPRs)
    const bf16x8* Wh8 = (const bf16x8*)Wh;
    const bf16x8* Wl8 = (const bf16x8*)Wl;
    bf16x8 bh[2][4], bl[2][4];
#pragma unroll
    for (int nt = 0; nt < 2; ++nt)
#pragma unroll
        for (int kt = 0; kt < 4; ++kt) {
            int fid = (2 * w + nt) * 4 + kt;
            bh[nt][kt] = Wh8[fid * 64 + l];
            bl[nt][kt] = Wl8[fid * 64 + l];
        }

    int r0 = id * 64;
    float asv0 = att_src[w * 32 + lr], asv1 = att_src[w * 32 + 16 + lr];
    float adv0 = att_dst[w * 32 + lr], adv1 = att_dst[w * 32 + 16 + lr];

#pragma unroll
    for (int mt = 0; mt < 4; ++mt) {
        int rb = r0 + mt * 16;
        int row = rb + lr;
        if (row >= N_NODES) row = N_NODES - 1;
        const float* xr = X + (size_t)row * 128;
        f32x4 acc0 = {0.f, 0.f, 0.f, 0.f};
        f32x4 acc1 = {0.f, 0.f, 0.f, 0.f};
#pragma unroll
        for (int kt = 0; kt < 4; ++kt) {
            int cb = kt * 32 + lq * 8;
            float4 f0 = *(const float4*)(xr + cb);
            float4 f1 = *(const float4*)(xr + cb + 4);
            float xs[8] = {f0.x, f0.y, f0.z, f0.w, f1.x, f1.y, f1.z, f1.w};
            bf16x8 ah, al;
#pragma unroll
            for (int s = 0; s < 8; ++s) {
                short h_, l_;
                split_bf(xs[s], h_, l_);
                ah[s] = h_;
                al[s] = l_;
            }
            acc0 = __builtin_amdgcn_mfma_f32_16x16x32_bf16(ah, bh[0][kt], acc0, 0, 0, 0);
            acc1 = __builtin_amdgcn_mfma_f32_16x16x32_bf16(ah, bh[1][kt], acc1, 0, 0, 0);
            acc0 = __builtin_amdgcn_mfma_f32_16x16x32_bf16(al, bh[0][kt], acc0, 0, 0, 0);
            acc1 = __builtin_amdgcn_mfma_f32_16x16x32_bf16(al, bh[1][kt], acc1, 0, 0, 0);
            acc0 = __builtin_amdgcn_mfma_f32_16x16x32_bf16(ah, bl[0][kt], acc0, 0, 0, 0);
            acc1 = __builtin_amdgcn_mfma_f32_16x16x32_bf16(ah, bl[1][kt], acc1, 0, 0, 0);
        }
        // epilogue: D row = rb + lq*4 + reg, cols = w*32 + {lr, 16+lr}
#pragma unroll
        for (int reg = 0; reg < 4; ++reg) {
            int r = rb + lq * 4 + reg;
            float v0 = acc0[reg], v1 = acc1[reg];
            float ps = v0 * asv0 + v1 * asv1;
            float pd = v0 * adv0 + v1 * adv1;
#pragma unroll
            for (int m = 1; m < 16; m <<= 1) {
                ps += __shfl_xor(ps, m, 64);
                pd += __shfl_xor(pd, m, 64);
            }
            if (r < N_NODES) {
                Y[(size_t)r * 128 + w * 32 + lr] = __float2bfloat16(v0);
                Y[(size_t)r * 128 + w * 32 + 16 + lr] = __float2bfloat16(v1);
                if (lr == 0) {
                    a_s[r * 4 + w] = ps;
                    a_d[r * 4 + w] = pd;
                }
            }
        }
    }
}

// ---------------- MFMA gemm2 (+att2 epilogue) ----------------
// block: 64 rows, 4 waves; wave w owns cols [16w, 16w+16). a_s2 spans all 64 cols -> LDS reduce.
__global__ __launch_bounds__(256, 3) void gemm2_mfma_kernel(
    const float* __restrict__ X, const short* __restrict__ Wh, const short* __restrict__ Wl,
    __hip_bfloat16* __restrict__ Y,
    const float* __restrict__ att_src, const float* __restrict__ att_dst,
    float* __restrict__ a_s, float* __restrict__ a_d) {
    __shared__ float psh[4][64];
    __shared__ float pdh[4][64];
    int tid = threadIdx.x;
    int w = tid >> 6;
    int l = tid & 63;
    int lr = l & 15;
    int lq = l >> 4;

    const bf16x8* Wh8 = (const bf16x8*)Wh;
    const bf16x8* Wl8 = (const bf16x8*)Wl;
    bf16x8 bh[4], bl[4];
#pragma unroll
    for (int kt = 0; kt < 4; ++kt) {
        int fid = w * 4 + kt;
        bh[kt] = Wh8[fid * 64 + l];
        bl[kt] = Wl8[fid * 64 + l];
    }

    int r0 = blockIdx.x * 64;
    float asv = att_src[w * 16 + lr];
    float adv = att_dst[w * 16 + lr];

    f32x4 acc[4];
#pragma unroll
    for (int mt = 0; mt < 4; ++mt) acc[mt] = (f32x4){0.f, 0.f, 0.f, 0.f};

#pragma unroll
    for (int mt = 0; mt < 4; ++mt) {
        int row = r0 + mt * 16 + lr;
        if (row >= N_NODES) row = N_NODES - 1;
        const float* xr = X + (size_t)row * 128;
#pragma unroll
        for (int kt = 0; kt < 4; ++kt) {
            int cb = kt * 32 + lq * 8;
            float4 f0 = *(const float4*)(xr + cb);
            float4 f1 = *(const float4*)(xr + cb + 4);
            float xs[8] = {f0.x, f0.y, f0.z, f0.w, f1.x, f1.y, f1.z, f1.w};
            bf16x8 ah, al;
#pragma unroll
            for (int s = 0; s < 8; ++s) {
                short h_, l_;
                split_bf(xs[s], h_, l_);
                ah[s] = h_;
                al[s] = l_;
            }
            acc[mt] = __builtin_amdgcn_mfma_f32_16x16x32_bf16(ah, bh[kt], acc[mt], 0, 0, 0);
            acc[mt] = __builtin_amdgcn_mfma_f32_16x16x32_bf16(al, bh[kt], acc[mt], 0, 0, 0);
            acc[mt] = __builtin_amdgcn_mfma_f32_16x16x32_bf16(ah, bl[kt], acc[mt], 0, 0, 0);
        }
    }

#pragma unroll
    for (int mt = 0; mt < 4; ++mt) {
#pragma unroll
        for (int reg = 0; reg < 4; ++reg) {
            int r = r0 + mt * 16 + lq * 4 + reg;
            float v = acc[mt][reg];
            float ps = v * asv;
            float pd = v * adv;
#pragma unroll
            for (int m = 1; m < 16; m <<= 1) {
                ps += __shfl_xor(ps, m, 64);
                pd += __shfl_xor(pd, m, 64);
            }
            if (r < N_NODES) Y[(size_t)r * 64 + w * 16 + lr] = __float2bfloat16(v);
            if (lr == 0) {
                psh[w][mt * 16 + lq * 4 + reg] = ps;
                pdh[w][mt * 16 + lq * 4 + reg] = pd;
            }
        }
    }
    __syncthreads();
    if (tid < 64) {
        int r = r0 + tid;
        if (r < N_NODES) {
            a_s[r] = psh[0][tid] + psh[1][tid] + psh[2][tid] + psh[3][tid];
            a_d[r] = pdh[0][tid] + pdh[1][tid] + pdh[2][tid] + pdh[3][tid];
        }
    }
}

// ---------------- scans ----------------
__global__ __launch_bounds__(256) void scan1_kernel(const int* __restrict__ deg,
                                                    int* __restrict__ rpl,
                                                    int* __restrict__ bsum) {
    int i = blockIdx.x * 256 + threadIdx.x;
    int v = (i < N_NODES) ? deg[i] : 0;
    int lane = threadIdx.x & 63;
    int w = threadIdx.x >> 6;
    int x = v;
#pragma unroll
    for (int off = 1; off < 64; off <<= 1) {
        int t = __shfl_up(x, off, 64);
        if (lane >= off) x += t;
    }
    __shared__ int wsum[4];
    if (lane == 63) wsum[w] = x;
    __syncthreads();
    int wo = 0;
    if (w > 0) wo += wsum[0];
    if (w > 1) wo += wsum[1];
    if (w > 2) wo += wsum[2];
    if (i <= N_NODES) rpl[i] = x - v + wo;  // local exclusive (incl. i==N_NODES)
    if (threadIdx.x == 255) bsum[blockIdx.x] = x + wo;
}

__global__ __launch_bounds__(256) void scan2_kernel(const int* __restrict__ bsum,
                                                    int* __restrict__ boff) {
    int i = threadIdx.x;
    int v = (i < NB_SCAN) ? bsum[i] : 0;
    int lane = threadIdx.x & 63;
    int w = threadIdx.x >> 6;
    int x = v;
#pragma unroll
    for (int off = 1; off < 64; off <<= 1) {
        int t = __shfl_up(x, off, 64);
        if (lane >= off) x += t;
    }
    __shared__ int wsum[4];
    if (lane == 63) wsum[w] = x;
    __syncthreads();
    int wo = 0;
    if (w > 0) wo += wsum[0];
    if (w > 1) wo += wsum[1];
    if (w > 2) wo += wsum[2];
    if (i < NB_SCAN) boff[i] = x - v + wo;
}

// ---------------- scatter (no atomics: rank precomputed) ----------------
__global__ __launch_bounds__(256) void scatter_kernel(const int* __restrict__ src,
                                                      const int* __restrict__ dst,
                                                      const int* __restrict__ rpl,
                                                      const int* __restrict__ boff,
                                                      const int* __restrict__ rank,
                                                      int* __restrict__ col) {
    int i = blockIdx.x * blockDim.x + threadIdx.x;
    if (i < N_EDGES) {
        int d = dst[i];
        int pos = rpl[d] + boff[d >> 8] + rank[i];
        col[pos] = src[i];
    }
}

// ---------------- aggregation layer 1 ----------------
__global__ __launch_bounds__(256) void agg1_kernel(const __hip_bfloat16* __restrict__ h,
                                                   const float* __restrict__ a_s,
                                                   const float* __restrict__ a_d,
                                                   const int* __restrict__ rpl,
                                                   const int* __restrict__ boff,
                                                   const int* __restrict__ col,
                                                   const float* __restrict__ b1,
                                                   const float* __restrict__ gamma,
                                                   const float* __restrict__ beta,
                                                   float* __restrict__ out) {
    __shared__ int colsh[4][CAP];
    __shared__ float wsh[4][CAP * 4];
    int wv = threadIdx.x >> 6;
    int lane = threadIdx.x & 63;
    int n = blockIdx.x * 4 + wv;
    int nn = (n < N_NODES) ? n : N_NODES - 1;
    int head = lane >> 4;
    int c = 2 * lane;

    const float4 ad4 = *(const float4*)&a_d[nn * 4];
    int beg = rpl[nn] + boff[nn >> 8];
    int end = rpl[nn + 1] + boff[(nn + 1) >> 8];
    int deg = end - beg;

    float den0 = 0.f, den1 = 0.f, den2 = 0.f, den3 = 0.f;
    for (int t = lane; t < deg; t += 64) {
        int s = col[beg + t];
        const float4 as4 = *(const float4*)&a_s[s * 4];
        float w0 = __expf(lrelu(as4.x + ad4.x));
        float w1 = __expf(lrelu(as4.y + ad4.y));
        float w2 = __expf(lrelu(as4.z + ad4.z));
        float w3 = __expf(lrelu(as4.w + ad4.w));
        if (t < CAP) {
            colsh[wv][t] = s;
            *(float4*)&wsh[wv][t * 4] = make_float4(w0, w1, w2, w3);
        }
        den0 += w0; den1 += w1; den2 += w2; den3 += w3;
    }
#pragma unroll
    for (int m = 1; m < 64; m <<= 1) {
        den0 += __shfl_xor(den0, m, 64);
        den1 += __shfl_xor(den1, m, 64);
        den2 += __shfl_xor(den2, m, 64);
        den3 += __shfl_xor(den3, m, 64);
    }
    float adh = (head == 0) ? ad4.x : (head == 1) ? ad4.y : (head == 2) ? ad4.z : ad4.w;
    float wself = __expf(lrelu(a_s[nn * 4 + head] + adh));
    float den = ((head == 0) ? den0 : (head == 1) ? den1 : (head == 2) ? den2 : den3) + wself;

    __syncthreads();

    float ax0 = 0.f, ay0 = 0.f, ax1 = 0.f, ay1 = 0.f;
    int m0 = (deg < CAP) ? deg : CAP;
    int j = 0;
    for (; j + 3 < m0; j += 4) {
        int s0 = colsh[wv][j + 0], s1 = colsh[wv][j + 1];
        int s2 = colsh[wv][j + 2], s3 = colsh[wv][j + 3];
        float w0 = wsh[wv][(j + 0) * 4 + head], w1 = wsh[wv][(j + 1) * 4 + head];
        float w2 = wsh[wv][(j + 2) * 4 + head], w3 = wsh[wv][(j + 3) * 4 + head];
        __hip_bfloat162 h0 = ((const __hip_bfloat162*)h)[(size_t)s0 * 64 + lane];
        __hip_bfloat162 h1 = ((const __hip_bfloat162*)h)[(size_t)s1 * 64 + lane];
        __hip_bfloat162 h2v = ((const __hip_bfloat162*)h)[(size_t)s2 * 64 + lane];
        __hip_bfloat162 h3 = ((const __hip_bfloat162*)h)[(size_t)s3 * 64 + lane];
        ax0 += w0 * bf2f(h0.x); ay0 += w0 * bf2f(h0.y);
        ax1 += w1 * bf2f(h1.x); ay1 += w1 * bf2f(h1.y);
        ax0 += w2 * bf2f(h2v.x); ay0 += w2 * bf2f(h2v.y);
        ax1 += w3 * bf2f(h3.x); ay1 += w3 * bf2f(h3.y);
    }
    for (; j < m0; ++j) {
        int s = colsh[wv][j];
        float w = wsh[wv][j * 4 + head];
        __hip_bfloat162 hv = ((const __hip_bfloat162*)h)[(size_t)s * 64 + lane];
        ax0 += w * bf2f(hv.x); ay0 += w * bf2f(hv.y);
    }
    for (; j < deg; ++j) {
        int s = col[beg + j];
        float w = __expf(lrelu(a_s[s * 4 + head] + adh));
        __hip_bfloat162 hv = ((const __hip_bfloat162*)h)[(size_t)s * 64 + lane];
        ax0 += w * bf2f(hv.x); ay0 += w * bf2f(hv.y);
    }
    {
        __hip_bfloat162 hv = ((const __hip_bfloat162*)h)[(size_t)nn * 64 + lane];
        ax0 += wself * bf2f(hv.x); ay0 += wself * bf2f(hv.y);
    }
    float inv = 1.f / den;
    float vx = (ax0 + ax1) * inv + b1[c];
    float vy = (ay0 + ay1) * inv + b1[c + 1];

    float s1 = vx + vy, s2 = vx * vx + vy * vy;
#pragma unroll
    for (int m = 1; m < 64; m <<= 1) {
        s1 += __shfl_xor(s1, m, 64);
        s2 += __shfl_xor(s2, m, 64);
    }
    float mean = s1 * (1.f / 128.f);
    float var = s2 * (1.f / 128.f) - mean * mean;
    float r = rsqrtf(var + LN_EPS);
    float ox = fmaxf(0.f, (vx - mean) * r * gamma[c] + beta[c]);
    float oy = fmaxf(0.f, (vy - mean) * r * gamma[c + 1] + beta[c + 1]);
    if (n < N_NODES) *(float2*)&out[(size_t)n * 128 + c] = make_float2(ox, oy);
}

// ---------------- aggregation layer 2 ----------------
__global__ __launch_bounds__(256) void agg2_kernel(const __hip_bfloat16* __restrict__ h,
                                                   const float* __restrict__ a_s,
                                                   const float* __restrict__ a_d,
                                                   const int* __restrict__ rpl,
                                                   const int* __restrict__ boff,
                                                   const int* __restrict__ col,
                                                   const float* __restrict__ b2,
                                                   const float* __restrict__ gamma,
                                                   const float* __restrict__ beta,
                                                   float* __restrict__ out) {
    __shared__ int colsh[4][CAP];
    __shared__ float wsh[4][CAP];
    int wv = threadIdx.x >> 6;
    int lane = threadIdx.x & 63;
    int n = blockIdx.x * 4 + wv;
    int nn = (n < N_NODES) ? n : N_NODES - 1;

    float adh = a_d[nn];
    int beg = rpl[nn] + boff[nn >> 8];
    int end = rpl[nn + 1] + boff[(nn + 1) >> 8];
    int deg = end - beg;

    float den = 0.f;
    for (int t = lane; t < deg; t += 64) {
        int s = col[beg + t];
        float w = __expf(lrelu(a_s[s] + adh));
        if (t < CAP) {
            colsh[wv][t] = s;
            wsh[wv][t] = w;
        }
        den += w;
    }
#pragma unroll
    for (int m = 1; m < 64; m <<= 1) den += __shfl_xor(den, m, 64);
    float wself = __expf(lrelu(a_s[nn] + adh));
    den += wself;

    __syncthreads();

    float a0 = 0.f, a1 = 0.f;
    int m0 = (deg < CAP) ? deg : CAP;
    int j = 0;
    for (; j + 3 < m0; j += 4) {
        int s0 = colsh[wv][j + 0], s1 = colsh[wv][j + 1];
        int s2 = colsh[wv][j + 2], s3 = colsh[wv][j + 3];
        float w0 = wsh[wv][j + 0], w1 = wsh[wv][j + 1];
        float w2 = wsh[wv][j + 2], w3 = wsh[wv][j + 3];
        a0 += w0 * bf2f(h[(size_t)s0 * 64 + lane]);
        a1 += w1 * bf2f(h[(size_t)s1 * 64 + lane]);
        a0 += w2 * bf2f(h[(size_t)s2 * 64 + lane]);
        a1 += w3 * bf2f(h[(size_t)s3 * 64 + lane]);
    }
    for (; j < m0; ++j) {
        a0 += wsh[wv][j] * bf2f(h[(size_t)colsh[wv][j] * 64 + lane]);
    }
    for (; j < deg; ++j) {
        int s = col[beg + j];
        float w = __expf(lrelu(a_s[s] + adh));
        a0 += w * bf2f(h[(size_t)s * 64 + lane]);
    }
    a0 += wself * bf2f(h[(size_t)nn * 64 + lane]);

    float v = (a0 + a1) / den + b2[lane];

    float s1 = v, s2 = v * v;
#pragma unroll
    for (int m = 1; m < 64; m <<= 1) {
        s1 += __shfl_xor(s1, m, 64);
        s2 += __shfl_xor(s2, m, 64);
    }
    float mean = s1 * (1.f / 64.f);
    float var = s2 * (1.f / 64.f) - mean * mean;
    float r = rsqrtf(var + LN_EPS);
    if (n < N_NODES) out[(size_t)n * 64 + lane] = (v - mean) * r * gamma[lane] + beta[lane];
}

// ---------------- host ----------------
extern "C" void kernel_launch(void* const* d_in, const int* in_sizes, int n_in,
                              void* d_out, int out_size, void* d_ws, size_t ws_size,
                              hipStream_t stream) {
    const float* x        = (const float*)d_in[0];
    const int*   ei       = (const int*)d_in[1];
    const float* W1       = (const float*)d_in[2];
    const float* att_src1 = (const float*)d_in[3];
    const float* att_dst1 = (const float*)d_in[4];
    const float* b1       = (const float*)d_in[5];
    const float* gamma1   = (const float*)d_in[6];
    const float* beta1    = (const float*)d_in[7];
    const float* W2       = (const float*)d_in[8];
    const float* att_src2 = (const float*)d_in[9];
    const float* att_dst2 = (const float*)d_in[10];
    const float* b2       = (const float*)d_in[11];
    const float* gamma2   = (const float*)d_in[12];
    const float* beta2    = (const float*)d_in[13];
    const int* src = ei;
    const int* dst = ei + N_EDGES;
    float* out = (float*)d_out;

    char* ws = (char*)d_ws;
    size_t off = 0;
    auto alloc = [&](size_t bytes) -> void* {
        void* p = ws + off;
        off += bytes;
        off = (off + 255) & ~(size_t)255;
        return p;
    };
    __hip_bfloat16* h1pre = (__hip_bfloat16*)alloc((size_t)N_NODES * 128 * 2);
    __hip_bfloat16* h2pre = (__hip_bfloat16*)alloc((size_t)N_NODES * 64 * 2);
    float* a_s1   = (float*)alloc((size_t)N_NODES * 4 * 4);
    float* a_d1   = (float*)alloc((size_t)N_NODES * 4 * 4);
    float* h1n    = (float*)alloc((size_t)N_NODES * 128 * 4);
    float* a_s2   = (float*)alloc((size_t)N_NODES * 4);
    float* a_d2   = (float*)alloc((size_t)N_NODES * 4);
    int* deg      = (int*)alloc((size_t)N_NODES * 4);
    int* rpl      = (int*)alloc((size_t)(N_NODES + 1) * 4);
    int* col      = (int*)alloc((size_t)N_EDGES * 4);
    int* rank     = (int*)alloc((size_t)N_EDGES * 4);
    int* bsum     = (int*)alloc((size_t)NB_SCAN * 4);
    int* boff     = (int*)alloc((size_t)NB_SCAN * 4);
    short* W1h    = (short*)alloc((size_t)16384 * 2);
    short* W1l    = (short*)alloc((size_t)16384 * 2);
    short* W2h    = (short*)alloc((size_t)8192 * 2);
    short* W2l    = (short*)alloc((size_t)8192 * 2);

    hipMemsetAsync(deg, 0, (size_t)N_NODES * 4, stream);

    const int EB = (N_EDGES + 255) / 256;
    const int NWB = (N_NODES + 3) / 4;

    wprep_kernel<<<96, 256, 0, stream>>>(W1, W2, W1h, W1l, W2h, W2l);

    // K1: MFMA gemm1 + att1 epilogue interleaved with degree/rank
    gemm1_mfma_degree_kernel<<<GB1N + DEGB, 256, 0, stream>>>(
        x, W1h, W1l, h1pre, att_src1, att_dst1, a_s1, a_d1, dst, deg, rank);
    scan1_kernel<<<NB_SCAN, 256, 0, stream>>>(deg, rpl, bsum);
    scan2_kernel<<<1, 256, 0, stream>>>(bsum, boff);
    scatter_kernel<<<EB, 256, 0, stream>>>(src, dst, rpl, boff, rank, col);

    agg1_kernel<<<NWB, 256, 0, stream>>>(h1pre, a_s1, a_d1, rpl, boff, col, b1, gamma1, beta1, h1n);

    gemm2_mfma_kernel<<<GB2N, 256, 0, stream>>>(
        h1n, W2h, W2l, h2pre, att_src2, att_dst2, a_s2, a_d2);
    agg2_kernel<<<NWB, 256, 0, stream>>>(h2pre, a_s2, a_d2, rpl, boff, col, b2, gamma2, beta2, out);
}

// Round 2
// 248.579 us; speedup vs baseline: 1.0164x; 1.0042x over previous
//
#include <hip/hip_runtime.h>
#include <hip/hip_bf16.h>
#include <math.h>

#define N_NODES 50000
#define N_EDGES 800000
#define HEADS 4
#define HID 32
#define D1 128
#define D2 64
#define NEG_SLOPE 0.2f
#define LN_EPS 1e-5f

#define NB_SCAN ((N_NODES + 255) / 256)  // 196
#define CAP 64
#define GB1N 782                          // ceil(50000/64) gemm1 row-blocks
#define GB2N 782                          // gemm2 row-blocks
#define DEGB 782                          // degree blocks: 782*256*4 = 800768 >= N_EDGES
#define ILV (2 * GB1N)                    // 1564: interleave range for gemm/degree
#define DEGPAD 16                         // one counter per 64B cacheline

typedef __attribute__((ext_vector_type(8))) short bf16x8;
typedef __attribute__((ext_vector_type(4))) float f32x4;

__device__ __forceinline__ float lrelu(float x) { return x > 0.f ? x : NEG_SLOPE * x; }
__device__ __forceinline__ float bf2f(__hip_bfloat16 v) { return __bfloat162float(v); }

__device__ __forceinline__ short f2bf_s(float x) {
    union { __hip_bfloat16 h; short s; } u;
    u.h = __float2bfloat16(x);
    return u.s;
}
__device__ __forceinline__ float bfs2f(short s) {
    union { unsigned u; float f; } v;
    v.u = ((unsigned)(unsigned short)s) << 16;
    return v.f;
}
__device__ __forceinline__ void split_bf(float x, short& hi, short& lo) {
    hi = f2bf_s(x);
    lo = f2bf_s(x - bfs2f(hi));
}

// ---------------- W prep: fragment-ordered bf16 hi/lo splits ----------------
// frag layout: frag_id = nt*4 + kt ; elem offset = fid*512 + l*8 + s
// value = W[kt*32 + (l>>4)*8 + s][nt*16 + (l&15)]
__global__ __launch_bounds__(256) void wprep_kernel(const float* __restrict__ W1,
                                                    const float* __restrict__ W2,
                                                    short* __restrict__ W1h, short* __restrict__ W1l,
                                                    short* __restrict__ W2h, short* __restrict__ W2l) {
    int idx = blockIdx.x * 256 + threadIdx.x;
    if (idx < 16384) {  // W1: 8 nt * 4 kt * 512
        int s = idx & 7, l = (idx >> 3) & 63, fid = idx >> 9;
        int kt = fid & 3, nt = fid >> 2;
        int k = kt * 32 + (l >> 4) * 8 + s;
        int n = nt * 16 + (l & 15);
        short hi, lo;
        split_bf(W1[k * 128 + n], hi, lo);
        W1h[idx] = hi;
        W1l[idx] = lo;
    } else if (idx < 16384 + 8192) {  // W2: 4 nt * 4 kt * 512
        int j = idx - 16384;
        int s = j & 7, l = (j >> 3) & 63, fid = j >> 9;
        int kt = fid & 3, nt = fid >> 2;
        int k = kt * 32 + (l >> 4) * 8 + s;
        int n = nt * 16 + (l & 15);
        short hi, lo;
        split_bf(W2[k * 64 + n], hi, lo);
        W2h[j] = hi;
        W2l[j] = lo;
    }
}

// ---------------- K1: MFMA gemm1 (+att1 epilogue) interleaved with degree/rank ----------------
// gemm block: 64 rows, 4 waves; wave w = head w owns cols [32w, 32w+32).
// 3-term bf16 split MFMA: xh*wh + xl*wh + xh*wl  (err ~2^-18, fp32-equivalent)
// degree counters padded: one per 64B line -> no same-line RMW serialization at coherence point
__global__ __launch_bounds__(256, 3) void gemm1_mfma_degree_kernel(
    const float* __restrict__ X, const short* __restrict__ Wh, const short* __restrict__ Wl,
    __hip_bfloat16* __restrict__ Y,
    const float* __restrict__ att_src, const float* __restrict__ att_dst,
    float* __restrict__ a_s, float* __restrict__ a_d,
    const int* __restrict__ dst, int* __restrict__ deg, int* __restrict__ rank) {
    int bid = blockIdx.x;
    bool isdeg;
    int id;
    if (bid < ILV) {  // interleave gemm/degree 1:1 so atomics spread over the dispatch
        isdeg = (bid & 1);
        id = bid >> 1;
    } else {
        isdeg = true;
        id = bid - ILV + GB1N;
    }
    if (isdeg) {
        int t0 = id * 256 + threadIdx.x;
        const int stride = DEGB * 256;
#pragma unroll
        for (int u = 0; u < 4; ++u) {
            int i = t0 + u * stride;
            if (i < N_EDGES) rank[i] = atomicAdd(&deg[dst[i] * DEGPAD], 1);
        }
        return;
    }

    int tid = threadIdx.x;
    int w = tid >> 6;   // wave == head
    int l = tid & 63;
    int lr = l & 15;    // A: row-in-tile ; B/D: col-in-tile
    int lq = l >> 4;    // k-chunk / D row-group

    // persistent B fragments (8 hi + 8 lo = 64 VGPRs)
    const bf16x8* Wh8 = (const bf16x8*)Wh;
    const bf16x8* Wl8 = (const bf16x8*)Wl;
    bf16x8 bh[2][4], bl[2][4];
#pragma unroll
    for (int nt = 0; nt < 2; ++nt)
#pragma unroll
        for (int kt = 0; kt < 4; ++kt) {
            int fid = (2 * w + nt) * 4 + kt;
            bh[nt][kt] = Wh8[fid * 64 + l];
            bl[nt][kt] = Wl8[fid * 64 + l];
        }

    int r0 = id * 64;
    float asv0 = att_src[w * 32 + lr], asv1 = att_src[w * 32 + 16 + lr];
    float adv0 = att_dst[w * 32 + lr], adv1 = att_dst[w * 32 + 16 + lr];

#pragma unroll
    for (int mt = 0; mt < 4; ++mt) {
        int rb = r0 + mt * 16;
        int row = rb + lr;
        if (row >= N_NODES) row = N_NODES - 1;
        const float* xr = X + (size_t)row * 128;
        f32x4 acc0 = {0.f, 0.f, 0.f, 0.f};
        f32x4 acc1 = {0.f, 0.f, 0.f, 0.f};
#pragma unroll
        for (int kt = 0; kt < 4; ++kt) {
            int cb = kt * 32 + lq * 8;
            float4 f0 = *(const float4*)(xr + cb);
            float4 f1 = *(const float4*)(xr + cb + 4);
            float xs[8] = {f0.x, f0.y, f0.z, f0.w, f1.x, f1.y, f1.z, f1.w};
            bf16x8 ah, al;
#pragma unroll
            for (int s = 0; s < 8; ++s) {
                short h_, l_;
                split_bf(xs[s], h_, l_);
                ah[s] = h_;
                al[s] = l_;
            }
            acc0 = __builtin_amdgcn_mfma_f32_16x16x32_bf16(ah, bh[0][kt], acc0, 0, 0, 0);
            acc1 = __builtin_amdgcn_mfma_f32_16x16x32_bf16(ah, bh[1][kt], acc1, 0, 0, 0);
            acc0 = __builtin_amdgcn_mfma_f32_16x16x32_bf16(al, bh[0][kt], acc0, 0, 0, 0);
            acc1 = __builtin_amdgcn_mfma_f32_16x16x32_bf16(al, bh[1][kt], acc1, 0, 0, 0);
            acc0 = __builtin_amdgcn_mfma_f32_16x16x32_bf16(ah, bl[0][kt], acc0, 0, 0, 0);
            acc1 = __builtin_amdgcn_mfma_f32_16x16x32_bf16(ah, bl[1][kt], acc1, 0, 0, 0);
        }
        // epilogue: D row = rb + lq*4 + reg, cols = w*32 + {lr, 16+lr}
#pragma unroll
        for (int reg = 0; reg < 4; ++reg) {
            int r = rb + lq * 4 + reg;
            float v0 = acc0[reg], v1 = acc1[reg];
            float ps = v0 * asv0 + v1 * asv1;
            float pd = v0 * adv0 + v1 * adv1;
#pragma unroll
            for (int m = 1; m < 16; m <<= 1) {
                ps += __shfl_xor(ps, m, 64);
                pd += __shfl_xor(pd, m, 64);
            }
            if (r < N_NODES) {
                Y[(size_t)r * 128 + w * 32 + lr] = __float2bfloat16(v0);
                Y[(size_t)r * 128 + w * 32 + 16 + lr] = __float2bfloat16(v1);
                if (lr == 0) {
                    a_s[r * 4 + w] = ps;
                    a_d[r * 4 + w] = pd;
                }
            }
        }
    }
}

// ---------------- MFMA gemm2 (+att2 epilogue) ----------------
// block: 64 rows, 4 waves; wave w owns cols [16w, 16w+16). a_s2 spans all 64 cols -> LDS reduce.
__global__ __launch_bounds__(256, 3) void gemm2_mfma_kernel(
    const float* __restrict__ X, const short* __restrict__ Wh, const short* __restrict__ Wl,
    __hip_bfloat16* __restrict__ Y,
    const float* __restrict__ att_src, const float* __restrict__ att_dst,
    float* __restrict__ a_s, float* __restrict__ a_d) {
    __shared__ float psh[4][64];
    __shared__ float pdh[4][64];
    int tid = threadIdx.x;
    int w = tid >> 6;
    int l = tid & 63;
    int lr = l & 15;
    int lq = l >> 4;

    const bf16x8* Wh8 = (const bf16x8*)Wh;
    const bf16x8* Wl8 = (const bf16x8*)Wl;
    bf16x8 bh[4], bl[4];
#pragma unroll
    for (int kt = 0; kt < 4; ++kt) {
        int fid = w * 4 + kt;
        bh[kt] = Wh8[fid * 64 + l];
        bl[kt] = Wl8[fid * 64 + l];
    }

    int r0 = blockIdx.x * 64;
    float asv = att_src[w * 16 + lr];
    float adv = att_dst[w * 16 + lr];

    f32x4 acc[4];
#pragma unroll
    for (int mt = 0; mt < 4; ++mt) acc[mt] = (f32x4){0.f, 0.f, 0.f, 0.f};

#pragma unroll
    for (int mt = 0; mt < 4; ++mt) {
        int row = r0 + mt * 16 + lr;
        if (row >= N_NODES) row = N_NODES - 1;
        const float* xr = X + (size_t)row * 128;
#pragma unroll
        for (int kt = 0; kt < 4; ++kt) {
            int cb = kt * 32 + lq * 8;
            float4 f0 = *(const float4*)(xr + cb);
            float4 f1 = *(const float4*)(xr + cb + 4);
            float xs[8] = {f0.x, f0.y, f0.z, f0.w, f1.x, f1.y, f1.z, f1.w};
            bf16x8 ah, al;
#pragma unroll
            for (int s = 0; s < 8; ++s) {
                short h_, l_;
                split_bf(xs[s], h_, l_);
                ah[s] = h_;
                al[s] = l_;
            }
            acc[mt] = __builtin_amdgcn_mfma_f32_16x16x32_bf16(ah, bh[kt], acc[mt], 0, 0, 0);
            acc[mt] = __builtin_amdgcn_mfma_f32_16x16x32_bf16(al, bh[kt], acc[mt], 0, 0, 0);
            acc[mt] = __builtin_amdgcn_mfma_f32_16x16x32_bf16(ah, bl[kt], acc[mt], 0, 0, 0);
        }
    }

#pragma unroll
    for (int mt = 0; mt < 4; ++mt) {
#pragma unroll
        for (int reg = 0; reg < 4; ++reg) {
            int r = r0 + mt * 16 + lq * 4 + reg;
            float v = acc[mt][reg];
            float ps = v * asv;
            float pd = v * adv;
#pragma unroll
            for (int m = 1; m < 16; m <<= 1) {
                ps += __shfl_xor(ps, m, 64);
                pd += __shfl_xor(pd, m, 64);
            }
            if (r < N_NODES) Y[(size_t)r * 64 + w * 16 + lr] = __float2bfloat16(v);
            if (lr == 0) {
                psh[w][mt * 16 + lq * 4 + reg] = ps;
                pdh[w][mt * 16 + lq * 4 + reg] = pd;
            }
        }
    }
    __syncthreads();
    if (tid < 64) {
        int r = r0 + tid;
        if (r < N_NODES) {
            a_s[r] = psh[0][tid] + psh[1][tid] + psh[2][tid] + psh[3][tid];
            a_d[r] = pdh[0][tid] + pdh[1][tid] + pdh[2][tid] + pdh[3][tid];
        }
    }
}

// ---------------- scans ----------------
__global__ __launch_bounds__(256) void scan1_kernel(const int* __restrict__ deg,
                                                    int* __restrict__ rpl,
                                                    int* __restrict__ bsum) {
    int i = blockIdx.x * 256 + threadIdx.x;
    int v = (i < N_NODES) ? deg[i * DEGPAD] : 0;
    int lane = threadIdx.x & 63;
    int w = threadIdx.x >> 6;
    int x = v;
#pragma unroll
    for (int off = 1; off < 64; off <<= 1) {
        int t = __shfl_up(x, off, 64);
        if (lane >= off) x += t;
    }
    __shared__ int wsum[4];
    if (lane == 63) wsum[w] = x;
    __syncthreads();
    int wo = 0;
    if (w > 0) wo += wsum[0];
    if (w > 1) wo += wsum[1];
    if (w > 2) wo += wsum[2];
    if (i <= N_NODES) rpl[i] = x - v + wo;  // local exclusive (incl. i==N_NODES)
    if (threadIdx.x == 255) bsum[blockIdx.x] = x + wo;
}

__global__ __launch_bounds__(256) void scan2_kernel(const int* __restrict__ bsum,
                                                    int* __restrict__ boff) {
    int i = threadIdx.x;
    int v = (i < NB_SCAN) ? bsum[i] : 0;
    int lane = threadIdx.x & 63;
    int w = threadIdx.x >> 6;
    int x = v;
#pragma unroll
    for (int off = 1; off < 64; off <<= 1) {
        int t = __shfl_up(x, off, 64);
        if (lane >= off) x += t;
    }
    __shared__ int wsum[4];
    if (lane == 63) wsum[w] = x;
    __syncthreads();
    int wo = 0;
    if (w > 0) wo += wsum[0];
    if (w > 1) wo += wsum[1];
    if (w > 2) wo += wsum[2];
    if (i < NB_SCAN) boff[i] = x - v + wo;
}

// ---------------- scatter (no atomics: rank precomputed) ----------------
__global__ __launch_bounds__(256) void scatter_kernel(const int* __restrict__ src,
                                                      const int* __restrict__ dst,
                                                      const int* __restrict__ rpl,
                                                      const int* __restrict__ boff,
                                                      const int* __restrict__ rank,
                                                      int* __restrict__ col) {
    int i = blockIdx.x * blockDim.x + threadIdx.x;
    if (i < N_EDGES) {
        int d = dst[i];
        int pos = rpl[d] + boff[d >> 8] + rank[i];
        col[pos] = src[i];
    }
}

// ---------------- aggregation layer 1 ----------------
__global__ __launch_bounds__(256) void agg1_kernel(const __hip_bfloat16* __restrict__ h,
                                                   const float* __restrict__ a_s,
                                                   const float* __restrict__ a_d,
                                                   const int* __restrict__ rpl,
                                                   const int* __restrict__ boff,
                                                   const int* __restrict__ col,
                                                   const float* __restrict__ b1,
                                                   const float* __restrict__ gamma,
                                                   const float* __restrict__ beta,
                                                   float* __restrict__ out) {
    __shared__ int colsh[4][CAP];
    __shared__ float wsh[4][CAP * 4];
    int wv = threadIdx.x >> 6;
    int lane = threadIdx.x & 63;
    int n = blockIdx.x * 4 + wv;
    int nn = (n < N_NODES) ? n : N_NODES - 1;
    int head = lane >> 4;
    int c = 2 * lane;

    const float4 ad4 = *(const float4*)&a_d[nn * 4];
    int beg = rpl[nn] + boff[nn >> 8];
    int end = rpl[nn + 1] + boff[(nn + 1) >> 8];
    int deg = end - beg;

    float den0 = 0.f, den1 = 0.f, den2 = 0.f, den3 = 0.f;
    for (int t = lane; t < deg; t += 64) {
        int s = col[beg + t];
        const float4 as4 = *(const float4*)&a_s[s * 4];
        float w0 = __expf(lrelu(as4.x + ad4.x));
        float w1 = __expf(lrelu(as4.y + ad4.y));
        float w2 = __expf(lrelu(as4.z + ad4.z));
        float w3 = __expf(lrelu(as4.w + ad4.w));
        if (t < CAP) {
            colsh[wv][t] = s;
            *(float4*)&wsh[wv][t * 4] = make_float4(w0, w1, w2, w3);
        }
        den0 += w0; den1 += w1; den2 += w2; den3 += w3;
    }
#pragma unroll
    for (int m = 1; m < 64; m <<= 1) {
        den0 += __shfl_xor(den0, m, 64);
        den1 += __shfl_xor(den1, m, 64);
        den2 += __shfl_xor(den2, m, 64);
        den3 += __shfl_xor(den3, m, 64);
    }
    float adh = (head == 0) ? ad4.x : (head == 1) ? ad4.y : (head == 2) ? ad4.z : ad4.w;
    float wself = __expf(lrelu(a_s[nn * 4 + head] + adh));
    float den = ((head == 0) ? den0 : (head == 1) ? den1 : (head == 2) ? den2 : den3) + wself;

    __syncthreads();

    float ax0 = 0.f, ay0 = 0.f, ax1 = 0.f, ay1 = 0.f;
    int m0 = (deg < CAP) ? deg : CAP;
    int j = 0;
    for (; j + 3 < m0; j += 4) {
        int s0 = colsh[wv][j + 0], s1 = colsh[wv][j + 1];
        int s2 = colsh[wv][j + 2], s3 = colsh[wv][j + 3];
        float w0 = wsh[wv][(j + 0) * 4 + head], w1 = wsh[wv][(j + 1) * 4 + head];
        float w2 = wsh[wv][(j + 2) * 4 + head], w3 = wsh[wv][(j + 3) * 4 + head];
        __hip_bfloat162 h0 = ((const __hip_bfloat162*)h)[(size_t)s0 * 64 + lane];
        __hip_bfloat162 h1 = ((const __hip_bfloat162*)h)[(size_t)s1 * 64 + lane];
        __hip_bfloat162 h2v = ((const __hip_bfloat162*)h)[(size_t)s2 * 64 + lane];
        __hip_bfloat162 h3 = ((const __hip_bfloat162*)h)[(size_t)s3 * 64 + lane];
        ax0 += w0 * bf2f(h0.x); ay0 += w0 * bf2f(h0.y);
        ax1 += w1 * bf2f(h1.x); ay1 += w1 * bf2f(h1.y);
        ax0 += w2 * bf2f(h2v.x); ay0 += w2 * bf2f(h2v.y);
        ax1 += w3 * bf2f(h3.x); ay1 += w3 * bf2f(h3.y);
    }
    for (; j < m0; ++j) {
        int s = colsh[wv][j];
        float w = wsh[wv][j * 4 + head];
        __hip_bfloat162 hv = ((const __hip_bfloat162*)h)[(size_t)s * 64 + lane];
        ax0 += w * bf2f(hv.x); ay0 += w * bf2f(hv.y);
    }
    for (; j < deg; ++j) {
        int s = col[beg + j];
        float w = __expf(lrelu(a_s[s * 4 + head] + adh));
        __hip_bfloat162 hv = ((const __hip_bfloat162*)h)[(size_t)s * 64 + lane];
        ax0 += w * bf2f(hv.x); ay0 += w * bf2f(hv.y);
    }
    {
        __hip_bfloat162 hv = ((const __hip_bfloat162*)h)[(size_t)nn * 64 + lane];
        ax0 += wself * bf2f(hv.x); ay0 += wself * bf2f(hv.y);
    }
    float inv = 1.f / den;
    float vx = (ax0 + ax1) * inv + b1[c];
    float vy = (ay0 + ay1) * inv + b1[c + 1];

    float s1 = vx + vy, s2 = vx * vx + vy * vy;
#pragma unroll
    for (int m = 1; m < 64; m <<= 1) {
        s1 += __shfl_xor(s1, m, 64);
        s2 += __shfl_xor(s2, m, 64);
    }
    float mean = s1 * (1.f / 128.f);
    float var = s2 * (1.f / 128.f) - mean * mean;
    float r = rsqrtf(var + LN_EPS);
    float ox = fmaxf(0.f, (vx - mean) * r * gamma[c] + beta[c]);
    float oy = fmaxf(0.f, (vy - mean) * r * gamma[c + 1] + beta[c + 1]);
    if (n < N_NODES) *(float2*)&out[(size_t)n * 128 + c] = make_float2(ox, oy);
}

// ---------------- aggregation layer 2 ----------------
__global__ __launch_bounds__(256) void agg2_kernel(const __hip_bfloat16* __restrict__ h,
                                                   const float* __restrict__ a_s,
                                                   const float* __restrict__ a_d,
                                                   const int* __restrict__ rpl,
                                                   const int* __restrict__ boff,
                                                   const int* __restrict__ col,
                                                   const float* __restrict__ b2,
                                                   const float* __restrict__ gamma,
                                                   const float* __restrict__ beta,
                                                   float* __restrict__ out) {
    __shared__ int colsh[4][CAP];
    __shared__ float wsh[4][CAP];
    int wv = threadIdx.x >> 6;
    int lane = threadIdx.x & 63;
    int n = blockIdx.x * 4 + wv;
    int nn = (n < N_NODES) ? n : N_NODES - 1;

    float adh = a_d[nn];
    int beg = rpl[nn] + boff[nn >> 8];
    int end = rpl[nn + 1] + boff[(nn + 1) >> 8];
    int deg = end - beg;

    float den = 0.f;
    for (int t = lane; t < deg; t += 64) {
        int s = col[beg + t];
        float w = __expf(lrelu(a_s[s] + adh));
        if (t < CAP) {
            colsh[wv][t] = s;
            wsh[wv][t] = w;
        }
        den += w;
    }
#pragma unroll
    for (int m = 1; m < 64; m <<= 1) den += __shfl_xor(den, m, 64);
    float wself = __expf(lrelu(a_s[nn] + adh));
    den += wself;

    __syncthreads();

    float a0 = 0.f, a1 = 0.f;
    int m0 = (deg < CAP) ? deg : CAP;
    int j = 0;
    for (; j + 3 < m0; j += 4) {
        int s0 = colsh[wv][j + 0], s1 = colsh[wv][j + 1];
        int s2 = colsh[wv][j + 2], s3 = colsh[wv][j + 3];
        float w0 = wsh[wv][j + 0], w1 = wsh[wv][j + 1];
        float w2 = wsh[wv][j + 2], w3 = wsh[wv][j + 3];
        a0 += w0 * bf2f(h[(size_t)s0 * 64 + lane]);
        a1 += w1 * bf2f(h[(size_t)s1 * 64 + lane]);
        a0 += w2 * bf2f(h[(size_t)s2 * 64 + lane]);
        a1 += w3 * bf2f(h[(size_t)s3 * 64 + lane]);
    }
    for (; j < m0; ++j) {
        a0 += wsh[wv][j] * bf2f(h[(size_t)colsh[wv][j] * 64 + lane]);
    }
    for (; j < deg; ++j) {
        int s = col[beg + j];
        float w = __expf(lrelu(a_s[s] + adh));
        a0 += w * bf2f(h[(size_t)s * 64 + lane]);
    }
    a0 += wself * bf2f(h[(size_t)nn * 64 + lane]);

    float v = (a0 + a1) / den + b2[lane];

    float s1 = v, s2 = v * v;
#pragma unroll
    for (int m = 1; m < 64; m <<= 1) {
        s1 += __shfl_xor(s1, m, 64);
        s2 += __shfl_xor(s2, m, 64);
    }
    float mean = s1 * (1.f / 64.f);
    float var = s2 * (1.f / 64.f) - mean * mean;
    float r = rsqrtf(var + LN_EPS);
    if (n < N_NODES) out[(size_t)n * 64 + lane] = (v - mean) * r * gamma[lane] + beta[lane];
}

// ---------------- host ----------------
extern "C" void kernel_launch(void* const* d_in, const int* in_sizes, int n_in,
                              void* d_out, int out_size, void* d_ws, size_t ws_size,
                              hipStream_t stream) {
    const float* x        = (const float*)d_in[0];
    const int*   ei       = (const int*)d_in[1];
    const float* W1       = (const float*)d_in[2];
    const float* att_src1 = (const float*)d_in[3];
    const float* att_dst1 = (const float*)d_in[4];
    const float* b1       = (const float*)d_in[5];
    const float* gamma1   = (const float*)d_in[6];
    const float* beta1    = (const float*)d_in[7];
    const float* W2       = (const float*)d_in[8];
    const float* att_src2 = (const float*)d_in[9];
    const float* att_dst2 = (const float*)d_in[10];
    const float* b2       = (const float*)d_in[11];
    const float* gamma2   = (const float*)d_in[12];
    const float* beta2    = (const float*)d_in[13];
    const int* src = ei;
    const int* dst = ei + N_EDGES;
    float* out = (float*)d_out;

    char* ws = (char*)d_ws;
    size_t off = 0;
    auto alloc = [&](size_t bytes) -> void* {
        void* p = ws + off;
        off += bytes;
        off = (off + 255) & ~(size_t)255;
        return p;
    };
    __hip_bfloat16* h1pre = (__hip_bfloat16*)alloc((size_t)N_NODES * 128 * 2);
    __hip_bfloat16* h2pre = (__hip_bfloat16*)alloc((size_t)N_NODES * 64 * 2);
    float* a_s1   = (float*)alloc((size_t)N_NODES * 4 * 4);
    float* a_d1   = (float*)alloc((size_t)N_NODES * 4 * 4);
    float* h1n    = (float*)alloc((size_t)N_NODES * 128 * 4);
    float* a_s2   = (float*)alloc((size_t)N_NODES * 4);
    float* a_d2   = (float*)alloc((size_t)N_NODES * 4);
    int* deg      = (int*)alloc((size_t)N_NODES * 4 * DEGPAD);
    int* rpl      = (int*)alloc((size_t)(N_NODES + 1) * 4);
    int* col      = (int*)alloc((size_t)N_EDGES * 4);
    int* rank     = (int*)alloc((size_t)N_EDGES * 4);
    int* bsum     = (int*)alloc((size_t)NB_SCAN * 4);
    int* boff     = (int*)alloc((size_t)NB_SCAN * 4);
    short* W1h    = (short*)alloc((size_t)16384 * 2);
    short* W1l    = (short*)alloc((size_t)16384 * 2);
    short* W2h    = (short*)alloc((size_t)8192 * 2);
    short* W2l    = (short*)alloc((size_t)8192 * 2);

    hipMemsetAsync(deg, 0, (size_t)N_NODES * 4 * DEGPAD, stream);

    const int EB = (N_EDGES + 255) / 256;
    const int NWB = (N_NODES + 3) / 4;

    wprep_kernel<<<96, 256, 0, stream>>>(W1, W2, W1h, W1l, W2h, W2l);

    // K1: MFMA gemm1 + att1 epilogue interleaved with degree/rank
    gemm1_mfma_degree_kernel<<<GB1N + DEGB, 256, 0, stream>>>(
        x, W1h, W1l, h1pre, att_src1, att_dst1, a_s1, a_d1, dst, deg, rank);
    scan1_kernel<<<NB_SCAN, 256, 0, stream>>>(deg, rpl, bsum);
    scan2_kernel<<<1, 256, 0, stream>>>(bsum, boff);
    scatter_kernel<<<EB, 256, 0, stream>>>(src, dst, rpl, boff, rank, col);

    agg1_kernel<<<NWB, 256, 0, stream>>>(h1pre, a_s1, a_d1, rpl, boff, col, b1, gamma1, beta1, h1n);

    gemm2_mfma_kernel<<<GB2N, 256, 0, stream>>>(
        h1n, W2h, W2l, h2pre, att_src2, att_dst2, a_s2, a_d2);
    agg2_kernel<<<NWB, 256, 0, stream>>>(h2pre, a_s2, a_d2, rpl, boff, col, b2, gamma2, beta2, out);
}